// Round 1
// baseline (75.763 us; speedup 1.0000x reference)
//
#include <hip/hip_runtime.h>
#include <math.h>

// Problem constants (from setup_inputs): n=16, C=1, H=W=128, nobj=128
#define NN   16
#define NOBJ 128
#define HH   128
#define WW   128
#define TILE_W 32
#define TILE_H 8
// tiles per image: (128/32) * (128/8) = 4 * 16 = 64

__global__ __launch_bounds__(256) void centernet_gt_kernel(
    const float* __restrict__ bboxes,   // [NN, NOBJ, 5]
    float* __restrict__ out)            // [NN, 1, HH, WW]
{
    __shared__ int   s_cx[NOBJ];
    __shared__ int   s_cy[NOBJ];
    __shared__ int   s_r[NOBJ];
    __shared__ float s_m[NOBJ];   // -1/(2*sigma^2)
    __shared__ int   s_ok[NOBJ];

    const int tilesPerImg = (WW / TILE_W) * (HH / TILE_H); // 64
    const int tilesX      = WW / TILE_W;                   // 4

    int img  = blockIdx.x / tilesPerImg;
    int tile = blockIdx.x % tilesPerImg;
    int tx0  = (tile % tilesX) * TILE_W;
    int ty0  = (tile / tilesX) * TILE_H;

    int tid = threadIdx.x;

    // ---- Phase 1: per-object params into LDS (threads 0..127) ----
    if (tid < NOBJ) {
        const float* bb = bboxes + (img * NOBJ + tid) * 5;
        float x1 = bb[0] * 128.0f;
        float y1 = bb[1] * 128.0f;
        float x2 = bb[2] * 128.0f;
        float y2 = bb[3] * 128.0f;
        float v  = bb[4];
        float bw = x2 - x1;
        float bh = y2 - y1;

        // gaussian_radius(bw, bh, min_overlap=0.7) — mirror numpy f32 op order
        float b1 = bh + bw;
        float c1 = bw * bh * 0.3f / 1.7f;
        float r1 = (b1 + sqrtf(b1 * b1 - 4.0f * c1)) * 0.5f;

        float b2 = 2.0f * (bh + bw);
        float c2 = 0.3f * bw * bh;
        float r2 = (b2 + sqrtf(b2 * b2 - 16.0f * c2)) * 0.5f;

        float b3 = -1.4f * (bh + bw);          // -2*0.7*(h+w)
        float c3 = -0.3f * bw * bh;            // (0.7-1)*w*h
        float r3 = (b3 + sqrtf(b3 * b3 - 11.2f * c3)) * 0.5f;  // 4*a3 = 11.2

        float rad = fminf(fminf(r1, r2), r3);
        if (!(rad > 0.0f)) rad = 0.0f;          // nan_to_num + max(.,0)

        int cxi = (int)((x1 + x2) * 0.5f);      // trunc toward zero (nonneg)
        int cyi = (int)((y1 + y2) * 0.5f);
        int ri  = (int)rad;

        float sigma = (float)(2 * ri + 1) / 6.0f;

        s_cx[tid] = cxi;
        s_cy[tid] = cyi;
        s_r[tid]  = ri;
        s_m[tid]  = -1.0f / (2.0f * sigma * sigma);
        s_ok[tid] = (v == 1.0f) && (bw > 0.0f) && (bh > 0.0f);
    }
    __syncthreads();

    // ---- Phase 2: each thread owns one pixel of the tile ----
    int x = tx0 + (tid & (TILE_W - 1));
    int y = ty0 + (tid >> 5);

    float acc = 0.0f;
    #pragma unroll 4
    for (int o = 0; o < NOBJ; ++o) {
        if (!s_ok[o]) continue;
        int cx = s_cx[o], cy = s_cy[o], r = s_r[o];
        // block-uniform tile cull (all threads agree -> no divergence cost)
        if (cx + r < tx0 || cx - r >= tx0 + TILE_W ||
            cy + r < ty0 || cy - r >= ty0 + TILE_H) continue;
        int dx = x - cx;
        int dy = y - cy;
        if (dx >= -r && dx <= r && dy >= -r && dy <= r) {
            float d2 = (float)(dx * dx + dy * dy);
            float g  = expf(d2 * s_m[o]);
            acc = fmaxf(acc, g);
        }
    }

    out[(img * HH + y) * WW + x] = acc;
}

extern "C" void kernel_launch(void* const* d_in, const int* in_sizes, int n_in,
                              void* d_out, int out_size, void* d_ws, size_t ws_size,
                              hipStream_t stream) {
    // d_in[0] = hm [16,1,128,128] f32 (only shape matters, unused)
    // d_in[1] = bboxes [16,128,5] f32
    const float* bboxes = (const float*)d_in[1];
    float* out = (float*)d_out;

    const int tilesPerImg = (WW / TILE_W) * (HH / TILE_H); // 64
    dim3 grid(NN * tilesPerImg);                           // 1024 blocks
    dim3 block(TILE_W * TILE_H);                           // 256 threads
    centernet_gt_kernel<<<grid, block, 0, stream>>>(bboxes, out);
}

// Round 2
// 58.365 us; speedup vs baseline: 1.2981x; 1.2981x over previous
//
#include <hip/hip_runtime.h>
#include <math.h>

// Problem constants (from setup_inputs): n=16, C=1, H=W=128, nobj=128
#define NN   16
#define NOBJ 128
#define HH   128
#define WW   128
#define TILE_W 32
#define TILE_H 8
// tiles per image: (128/32) * (128/8) = 4 * 16 = 64

__global__ __launch_bounds__(256) void centernet_gt_kernel(
    const float* __restrict__ bboxes,   // [NN, NOBJ, 5]
    float* __restrict__ out)            // [NN, 1, HH, WW]
{
    // Compacted per-tile object list: .x=cx, .y=cy, .z=r, .w=bits(-1/(2*sigma^2))
    __shared__ int4 s_obj[NOBJ];
    __shared__ int  s_cnt;

    const int tilesPerImg = (WW / TILE_W) * (HH / TILE_H); // 64
    const int tilesX      = WW / TILE_W;                   // 4

    int img  = blockIdx.x / tilesPerImg;
    int tile = blockIdx.x % tilesPerImg;
    int tx0  = (tile % tilesX) * TILE_W;
    int ty0  = (tile / tilesX) * TILE_H;

    int tid = threadIdx.x;

    if (tid == 0) s_cnt = 0;
    __syncthreads();

    // ---- Phase 1: per-object params + tile cull + compaction (threads 0..127)
    if (tid < NOBJ) {
        const float* bb = bboxes + (img * NOBJ + tid) * 5;
        float x1 = bb[0] * 128.0f;
        float y1 = bb[1] * 128.0f;
        float x2 = bb[2] * 128.0f;
        float y2 = bb[3] * 128.0f;
        float v  = bb[4];
        float bw = x2 - x1;
        float bh = y2 - y1;

        // gaussian_radius(bw, bh, min_overlap=0.7) — mirror numpy f32 op order
        float b1 = bh + bw;
        float c1 = bw * bh * 0.3f / 1.7f;
        float r1 = (b1 + sqrtf(b1 * b1 - 4.0f * c1)) * 0.5f;

        float b2 = 2.0f * (bh + bw);
        float c2 = 0.3f * bw * bh;
        float r2 = (b2 + sqrtf(b2 * b2 - 16.0f * c2)) * 0.5f;

        float b3 = -1.4f * (bh + bw);          // -2*0.7*(h+w)
        float c3 = -0.3f * bw * bh;            // (0.7-1)*w*h
        float r3 = (b3 + sqrtf(b3 * b3 - 11.2f * c3)) * 0.5f;  // 4*a3 = 11.2

        float rad = fminf(fminf(r1, r2), r3);
        if (!(rad > 0.0f)) rad = 0.0f;          // nan_to_num + max(.,0)

        int cxi = (int)((x1 + x2) * 0.5f);      // trunc toward zero (nonneg)
        int cyi = (int)((y1 + y2) * 0.5f);
        int ri  = (int)rad;

        bool ok = (v == 1.0f) && (bw > 0.0f) && (bh > 0.0f);
        // tile AABB overlap cull (uniform per block, per-object per-lane here)
        bool hit = ok &&
                   (cxi + ri >= tx0) && (cxi - ri < tx0 + TILE_W) &&
                   (cyi + ri >= ty0) && (cyi - ri < ty0 + TILE_H);

        if (hit) {
            float sigma = (float)(2 * ri + 1) / 6.0f;
            float m = -1.0f / (2.0f * sigma * sigma);
            int pos = atomicAdd(&s_cnt, 1);     // LDS atomic; order irrelevant (max)
            s_obj[pos] = make_int4(cxi, cyi, ri, __float_as_int(m));
        }
    }
    __syncthreads();

    // ---- Phase 2: each thread owns one pixel of the tile ----
    int x = tx0 + (tid & (TILE_W - 1));
    int y = ty0 + (tid >> 5);

    int cnt = s_cnt;
    float acc = 0.0f;
    for (int o = 0; o < cnt; ++o) {
        int4 ob = s_obj[o];                     // one ds_read_b128 broadcast
        int dx = x - ob.x;
        int dy = y - ob.y;
        int r  = ob.z;
        if (dx >= -r && dx <= r && dy >= -r && dy <= r) {
            float d2 = (float)(dx * dx + dy * dy);
            acc = fmaxf(acc, expf(d2 * __int_as_float(ob.w)));
        }
    }

    out[(img * HH + y) * WW + x] = acc;
}

extern "C" void kernel_launch(void* const* d_in, const int* in_sizes, int n_in,
                              void* d_out, int out_size, void* d_ws, size_t ws_size,
                              hipStream_t stream) {
    // d_in[0] = hm [16,1,128,128] f32 (only shape matters, unused)
    // d_in[1] = bboxes [16,128,5] f32
    const float* bboxes = (const float*)d_in[1];
    float* out = (float*)d_out;

    const int tilesPerImg = (WW / TILE_W) * (HH / TILE_H); // 64
    dim3 grid(NN * tilesPerImg);                           // 1024 blocks
    dim3 block(TILE_W * TILE_H);                           // 256 threads
    centernet_gt_kernel<<<grid, block, 0, stream>>>(bboxes, out);
}